// Round 1
// baseline (378.859 us; speedup 1.0000x reference)
//
#include <hip/hip_runtime.h>
#include <hip/hip_bf16.h>
#include <cstdint>
#include <cstddef>

#define NROW 4096
#define DDIM 64
#define NM ((size_t)NROW * (size_t)NROW)

// S = log2(e)/eps, eps = 0.1
__device__ __constant__ float kS = 14.426950408889634f;
#define SCONST 14.426950408889634f
#define EPS_LN2 0.0693147180559945f   // eps * ln(2)

#if __has_builtin(__builtin_amdgcn_exp2f)
#define FEXP2(x) __builtin_amdgcn_exp2f(x)
#else
#define FEXP2(x) exp2f(x)
#endif
#if __has_builtin(__builtin_amdgcn_logf)
#define FLOG2(x) __builtin_amdgcn_logf(x)
#else
#define FLOG2(x) log2f(x)
#endif

// ---------------------------------------------------------------------------
// init: pe = eps*log p, qe = eps*log q, a = S*g = 0, row norms of x and y
// ---------------------------------------------------------------------------
__global__ void init_kernel(const float* __restrict__ x, const float* __restrict__ y,
                            const float* __restrict__ p, const float* __restrict__ q,
                            float* __restrict__ pe, float* __restrict__ qe,
                            float* __restrict__ a,
                            float* __restrict__ xn, float* __restrict__ yn) {
    int t = blockIdx.x * blockDim.x + threadIdx.x;
    if (t >= NROW) return;
    pe[t] = EPS_LN2 * FLOG2(p[t]);
    qe[t] = EPS_LN2 * FLOG2(q[t]);
    a[t] = 0.f;
    const float* xr = x + (size_t)t * DDIM;
    const float* yr = y + (size_t)t * DDIM;
    float sx = 0.f, sy = 0.f;
    for (int d = 0; d < DDIM; ++d) {
        sx = fmaf(xr[d], xr[d], sx);
        sy = fmaf(yr[d], yr[d], sy);
    }
    xn[t] = sx; yn[t] = sy;
}

// ---------------------------------------------------------------------------
// cost: C[i,j] = ||x_i||^2 + ||y_j||^2 - 2 x_i . y_j   (64x64 tile per block)
// optionally also writes CT (transposed) via LDS staging
// ---------------------------------------------------------------------------
__global__ __launch_bounds__(256) void cost_kernel(const float* __restrict__ x,
                                                   const float* __restrict__ y,
                                                   const float* __restrict__ xn,
                                                   const float* __restrict__ yn,
                                                   float* __restrict__ C,
                                                   float* __restrict__ CT) {
    __shared__ float xs[64 * 65];
    __shared__ float ys[64 * 65];
    int tid = threadIdx.x;
    int it = blockIdx.y, jt = blockIdx.x;
    // stage tiles (rows contiguous in global)
    for (int k = tid; k < 4096; k += 256) {
        int r = k >> 6, d = k & 63;
        xs[r * 65 + d] = x[(size_t)it * 4096 + k];
        ys[r * 65 + d] = y[(size_t)jt * 4096 + k];
    }
    __syncthreads();
    int rl = tid >> 4;   // 0..15
    int cl = tid & 15;   // 0..15
    float acc[4][4] = {};
    #pragma unroll 8
    for (int d = 0; d < 64; ++d) {
        float xv[4], yv[4];
        #pragma unroll
        for (int i = 0; i < 4; ++i) xv[i] = xs[(rl + 16 * i) * 65 + d];
        #pragma unroll
        for (int j = 0; j < 4; ++j) yv[j] = ys[(cl + 16 * j) * 65 + d];
        #pragma unroll
        for (int i = 0; i < 4; ++i)
            #pragma unroll
            for (int j = 0; j < 4; ++j)
                acc[i][j] = fmaf(xv[i], yv[j], acc[i][j]);
    }
    __syncthreads();   // done reading xs/ys
    // write C
    #pragma unroll
    for (int i = 0; i < 4; ++i) {
        int row = it * 64 + rl + 16 * i;
        float xni = xn[row];
        #pragma unroll
        for (int j = 0; j < 4; ++j) {
            int col = jt * 64 + cl + 16 * j;
            float cv = xni + yn[col] - 2.f * acc[i][j];
            C[(size_t)row * 4096 + col] = cv;
            acc[i][j] = cv;  // keep the final value for transpose staging
        }
    }
    if (CT != nullptr) {
        // stage tile into LDS (reuse xs) then write transposed, coalesced
        float* ts = xs;
        #pragma unroll
        for (int i = 0; i < 4; ++i)
            #pragma unroll
            for (int j = 0; j < 4; ++j)
                ts[(rl + 16 * i) * 65 + (cl + 16 * j)] = acc[i][j];
        __syncthreads();
        #pragma unroll
        for (int i = 0; i < 4; ++i) {
            int trow = jt * 64 + rl + 16 * i;       // CT row = original col
            #pragma unroll
            for (int j = 0; j < 4; ++j) {
                int tcol = it * 64 + cl + 16 * j;   // CT col = original row
                CT[(size_t)trow * 4096 + tcol] = ts[(cl + 16 * j) * 65 + (rl + 16 * i)];
            }
        }
    }
}

// ---------------------------------------------------------------------------
// one half-iteration: vout_i = pv_i - eps*ln2 * (m + log2 s) over row i of Mat,
// where terms are 2^(vin_j - S*Mat[i,j]).  vin/vout are the S-scaled potentials.
// wave per row, 4 rows per block.
// ---------------------------------------------------------------------------
__global__ __launch_bounds__(256) void pass_kernel(const float* __restrict__ Mat,
                                                   const float* __restrict__ vin,
                                                   const float* __restrict__ pv,
                                                   float* __restrict__ vout) {
    __shared__ float sv[4096];
    int tid = threadIdx.x;
    for (int k = tid; k < 4096; k += 256) sv[k] = vin[k];
    __syncthreads();
    int w = tid >> 6, lane = tid & 63;
    int i = blockIdx.x * 4 + w;
    const float* Mrow = Mat + (size_t)i * 4096;
    float m = -1e30f, s = 0.f;
    #pragma unroll 8
    for (int k = 0; k < 64; ++k) {
        int j = lane + 64 * k;
        float u = fmaf(-SCONST, Mrow[j], sv[j]);
        float d = u - m;
        if (d <= 8.f) {
            s += FEXP2(d);
        } else {
            s = fmaf(s, FEXP2(-d), 1.f);
            m = u;
        }
    }
    // 64-lane butterfly combine of (m, s)
    #pragma unroll
    for (int off = 32; off >= 1; off >>= 1) {
        float om = __shfl_xor(m, off);
        float os = __shfl_xor(s, off);
        float nm = fmaxf(m, om);
        s = s * FEXP2(m - nm) + os * FEXP2(om - nm);
        m = nm;
    }
    if (lane == 0) {
        float f = pv[i] - EPS_LN2 * (m + FLOG2(s));
        vout[i] = SCONST * f;   // store S-scaled potential
    }
}

// ---------------------------------------------------------------------------
// fallback column pass (no CT available): 64 blocks x 1024 threads,
// each block owns 64 columns over all 4096 rows.
// ---------------------------------------------------------------------------
__global__ __launch_bounds__(1024) void col_slow_kernel(const float* __restrict__ C,
                                                        const float* __restrict__ b,
                                                        const float* __restrict__ qe,
                                                        float* __restrict__ a) {
    __shared__ float sb[4096];
    __shared__ float sm[16][64];
    __shared__ float ss[16][64];
    int tid = threadIdx.x;
    for (int k = tid; k < 4096; k += 1024) sb[k] = b[k];
    __syncthreads();
    int w = tid >> 6, lane = tid & 63;
    int j = blockIdx.x * 64 + lane;
    float m = -1e30f, s = 0.f;
    #pragma unroll 4
    for (int r = 0; r < 256; ++r) {
        int i = (w << 8) + r;
        float u = fmaf(-SCONST, C[(size_t)i * 4096 + j], sb[i]);
        float d = u - m;
        if (d <= 8.f) {
            s += FEXP2(d);
        } else {
            s = fmaf(s, FEXP2(-d), 1.f);
            m = u;
        }
    }
    sm[w][lane] = m; ss[w][lane] = s;
    __syncthreads();
    if (tid < 64) {
        float m0 = sm[0][tid], s0 = ss[0][tid];
        #pragma unroll
        for (int w2 = 1; w2 < 16; ++w2) {
            float m1 = sm[w2][tid], s1 = ss[w2][tid];
            float nm = fmaxf(m0, m1);
            s0 = s0 * FEXP2(m0 - nm) + s1 * FEXP2(m1 - nm);
            m0 = nm;
        }
        int jj = blockIdx.x * 64 + tid;
        float g = qe[jj] - EPS_LN2 * (m0 + FLOG2(s0));
        a[jj] = SCONST * g;
    }
}

// ---------------------------------------------------------------------------
// P = exp2(b_i + a_j - S*C_ij) written to out, partial sums of P*C per block
// ---------------------------------------------------------------------------
__global__ __launch_bounds__(256) void pcost_kernel(const float* __restrict__ C,
                                                    const float* __restrict__ a,
                                                    const float* __restrict__ b,
                                                    float* __restrict__ P,
                                                    float* __restrict__ part) {
    int tid = threadIdx.x;
    size_t base = (size_t)blockIdx.x * 256 + tid;
    float acc = 0.f;
    #pragma unroll
    for (int k = 0; k < 16; ++k) {
        size_t idx = base + (size_t)k * (4096u * 256u);
        int i = (int)(idx >> 12);
        int j = (int)(idx & 4095);
        float c = C[idx];
        float Pv = FEXP2(fmaf(-SCONST, c, b[i] + a[j]));
        P[idx] = Pv;
        acc = fmaf(Pv, c, acc);
    }
    #pragma unroll
    for (int off = 32; off >= 1; off >>= 1) acc += __shfl_xor(acc, off);
    __shared__ float sw[4];
    if ((tid & 63) == 0) sw[tid >> 6] = acc;
    __syncthreads();
    if (tid == 0) part[blockIdx.x] = (sw[0] + sw[1]) + (sw[2] + sw[3]);
}

__global__ __launch_bounds__(256) void reduce_kernel(const float* __restrict__ part,
                                                     float* __restrict__ out0) {
    int tid = threadIdx.x;
    float acc = 0.f;
    #pragma unroll
    for (int k = 0; k < 16; ++k) acc += part[tid + 256 * k];
    #pragma unroll
    for (int off = 32; off >= 1; off >>= 1) acc += __shfl_xor(acc, off);
    __shared__ float sw[4];
    if ((tid & 63) == 0) sw[tid >> 6] = acc;
    __syncthreads();
    if (tid == 0) out0[0] = (sw[0] + sw[1]) + (sw[2] + sw[3]);
}

// ---------------------------------------------------------------------------
extern "C" void kernel_launch(void* const* d_in, const int* in_sizes, int n_in,
                              void* d_out, int out_size, void* d_ws, size_t ws_size,
                              hipStream_t stream) {
    const float* x = (const float*)d_in[0];
    const float* y = (const float*)d_in[1];
    const float* p = (const float*)d_in[2];
    const float* q = (const float*)d_in[3];
    float* out = (float*)d_out;
    char* ws = (char*)d_ws;

    float* pe   = (float*)(ws + 0 * 16384);
    float* qe   = (float*)(ws + 1 * 16384);
    float* a    = (float*)(ws + 2 * 16384);   // S * g
    float* b    = (float*)(ws + 3 * 16384);   // S * f
    float* xn   = (float*)(ws + 4 * 16384);
    float* yn   = (float*)(ws + 5 * 16384);
    float* part = (float*)(ws + 6 * 16384);
    const size_t SMALL = 128 * 1024;
    const size_t CBYTES = NM * sizeof(float);

    float* C;
    float* CT;
    if (ws_size >= SMALL + CBYTES) {
        C  = (float*)(ws + SMALL);
        CT = out + 1;                 // transposed copy lives in P region until the end
    } else {
        C  = out + 1;                 // fallback: C in the P region
        CT = nullptr;
    }

    init_kernel<<<16, 256, 0, stream>>>(x, y, p, q, pe, qe, a, xn, yn);
    cost_kernel<<<dim3(64, 64), 256, 0, stream>>>(x, y, xn, yn, C, CT);

    for (int iter = 0; iter < 10; ++iter) {
        // row pass: b = S*f from C rows with vin = a
        pass_kernel<<<1024, 256, 0, stream>>>(C, a, pe, b);
        // col pass: a = S*g from columns (CT rows if available)
        if (CT != nullptr) {
            pass_kernel<<<1024, 256, 0, stream>>>(CT, b, qe, a);
        } else {
            col_slow_kernel<<<64, 1024, 0, stream>>>(C, b, qe, a);
        }
    }

    pcost_kernel<<<4096, 256, 0, stream>>>(C, a, b, out + 1, part);
    reduce_kernel<<<1, 256, 0, stream>>>(part, out);
}

// Round 2
// 324.887 us; speedup vs baseline: 1.1661x; 1.1661x over previous
//
#include <hip/hip_runtime.h>
#include <hip/hip_bf16.h>
#include <cstdint>
#include <cstddef>

#define NROW 4096
#define DDIM 64
#define NM ((size_t)NROW * (size_t)NROW)

// S = log2(e)/eps, eps = 0.1
#define SCONST 14.426950408889634f
#define EPS_LN2 0.0693147180559945f   // eps * ln(2)

#if __has_builtin(__builtin_amdgcn_exp2f)
#define FEXP2(x) __builtin_amdgcn_exp2f(x)
#else
#define FEXP2(x) exp2f(x)
#endif
#if __has_builtin(__builtin_amdgcn_logf)
#define FLOG2(x) __builtin_amdgcn_logf(x)
#else
#define FLOG2(x) log2f(x)
#endif

// ---------------------------------------------------------------------------
// init: pe = eps*log p, qe = eps*log q, a = S*g = 0, row norms of x and y
// ---------------------------------------------------------------------------
__global__ void init_kernel(const float* __restrict__ x, const float* __restrict__ y,
                            const float* __restrict__ p, const float* __restrict__ q,
                            float* __restrict__ pe, float* __restrict__ qe,
                            float* __restrict__ a,
                            float* __restrict__ xn, float* __restrict__ yn) {
    int t = blockIdx.x * blockDim.x + threadIdx.x;
    if (t >= NROW) return;
    pe[t] = EPS_LN2 * FLOG2(p[t]);
    qe[t] = EPS_LN2 * FLOG2(q[t]);
    a[t] = 0.f;
    const float* xr = x + (size_t)t * DDIM;
    const float* yr = y + (size_t)t * DDIM;
    float sx = 0.f, sy = 0.f;
    for (int d = 0; d < DDIM; ++d) {
        sx = fmaf(xr[d], xr[d], sx);
        sy = fmaf(yr[d], yr[d], sy);
    }
    xn[t] = sx; yn[t] = sy;
}

// ---------------------------------------------------------------------------
// cost: C[i,j] = ||x_i||^2 + ||y_j||^2 - 2 x_i . y_j   (64x64 tile per block)
// optionally also writes CT (transposed) via LDS staging
// ---------------------------------------------------------------------------
__global__ __launch_bounds__(256) void cost_kernel(const float* __restrict__ x,
                                                   const float* __restrict__ y,
                                                   const float* __restrict__ xn,
                                                   const float* __restrict__ yn,
                                                   float* __restrict__ C,
                                                   float* __restrict__ CT) {
    __shared__ float xs[64 * 65];
    __shared__ float ys[64 * 65];
    int tid = threadIdx.x;
    int it = blockIdx.y, jt = blockIdx.x;
    for (int k = tid; k < 4096; k += 256) {
        int r = k >> 6, d = k & 63;
        xs[r * 65 + d] = x[(size_t)it * 4096 + k];
        ys[r * 65 + d] = y[(size_t)jt * 4096 + k];
    }
    __syncthreads();
    int rl = tid >> 4;   // 0..15
    int cl = tid & 15;   // 0..15
    float acc[4][4] = {};
    #pragma unroll 8
    for (int d = 0; d < 64; ++d) {
        float xv[4], yv[4];
        #pragma unroll
        for (int i = 0; i < 4; ++i) xv[i] = xs[(rl + 16 * i) * 65 + d];
        #pragma unroll
        for (int j = 0; j < 4; ++j) yv[j] = ys[(cl + 16 * j) * 65 + d];
        #pragma unroll
        for (int i = 0; i < 4; ++i)
            #pragma unroll
            for (int j = 0; j < 4; ++j)
                acc[i][j] = fmaf(xv[i], yv[j], acc[i][j]);
    }
    __syncthreads();
    #pragma unroll
    for (int i = 0; i < 4; ++i) {
        int row = it * 64 + rl + 16 * i;
        float xni = xn[row];
        #pragma unroll
        for (int j = 0; j < 4; ++j) {
            int col = jt * 64 + cl + 16 * j;
            float cv = xni + yn[col] - 2.f * acc[i][j];
            C[(size_t)row * 4096 + col] = cv;
            acc[i][j] = cv;
        }
    }
    if (CT != nullptr) {
        float* ts = xs;
        #pragma unroll
        for (int i = 0; i < 4; ++i)
            #pragma unroll
            for (int j = 0; j < 4; ++j)
                ts[(rl + 16 * i) * 65 + (cl + 16 * j)] = acc[i][j];
        __syncthreads();
        #pragma unroll
        for (int i = 0; i < 4; ++i) {
            int trow = jt * 64 + rl + 16 * i;
            #pragma unroll
            for (int j = 0; j < 4; ++j) {
                int tcol = it * 64 + cl + 16 * j;
                CT[(size_t)trow * 4096 + tcol] = ts[(cl + 16 * j) * 65 + (rl + 16 * i)];
            }
        }
    }
}

// ---------------------------------------------------------------------------
// vectorized half-iteration: 4 rows per block, 256 threads. Branchless online
// base-2 LSE over float4 chunks; potential vector read once per 4 rows.
// Mat4 must be 16B-aligned. vout_i = S*(pv_i - eps*ln2*(m + log2 s)).
// ---------------------------------------------------------------------------
__global__ __launch_bounds__(256) void pass_vec(const float4* __restrict__ Mat4,
                                                const float4* __restrict__ vin4,
                                                const float* __restrict__ pv,
                                                float* __restrict__ vout) {
    int tid = threadIdx.x;
    int lane = tid & 63, w = tid >> 6;
    int i0 = blockIdx.x * 4;
    const float4* r0 = Mat4 + (size_t)i0 * 1024;
    const float4* r1 = r0 + 1024;
    const float4* r2 = r1 + 1024;
    const float4* r3 = r2 + 1024;
    float m[4] = {-1e30f, -1e30f, -1e30f, -1e30f};
    float s[4] = {0.f, 0.f, 0.f, 0.f};
    #pragma unroll
    for (int k = 0; k < 4; ++k) {
        int j = tid + 256 * k;
        float4 v4 = vin4[j];
        float4 c[4];
        c[0] = r0[j]; c[1] = r1[j]; c[2] = r2[j]; c[3] = r3[j];
        #pragma unroll
        for (int r = 0; r < 4; ++r) {
            float u0 = fmaf(-SCONST, c[r].x, v4.x);
            float u1 = fmaf(-SCONST, c[r].y, v4.y);
            float u2 = fmaf(-SCONST, c[r].z, v4.z);
            float u3 = fmaf(-SCONST, c[r].w, v4.w);
            float m4 = fmaxf(fmaxf(u0, u1), fmaxf(u2, u3));
            float nm = fmaxf(m[r], m4);
            float e = (FEXP2(u0 - nm) + FEXP2(u1 - nm)) + (FEXP2(u2 - nm) + FEXP2(u3 - nm));
            s[r] = fmaf(s[r], FEXP2(m[r] - nm), e);
            m[r] = nm;
        }
    }
    __shared__ float sm[4][4];
    __shared__ float ss[4][4];
    #pragma unroll
    for (int r = 0; r < 4; ++r) {
        float mr = m[r], sr = s[r];
        #pragma unroll
        for (int off = 32; off >= 1; off >>= 1) {
            float om = __shfl_xor(mr, off);
            float os = __shfl_xor(sr, off);
            float nm = fmaxf(mr, om);
            sr = fmaf(sr, FEXP2(mr - nm), os * FEXP2(om - nm));
            mr = nm;
        }
        if (lane == 0) { sm[w][r] = mr; ss[w][r] = sr; }
    }
    __syncthreads();
    if (tid < 4) {
        float m0 = sm[0][tid], s0 = ss[0][tid];
        #pragma unroll
        for (int w2 = 1; w2 < 4; ++w2) {
            float m1 = sm[w2][tid], s1 = ss[w2][tid];
            float nm = fmaxf(m0, m1);
            s0 = fmaf(s0, FEXP2(m0 - nm), s1 * FEXP2(m1 - nm));
            m0 = nm;
        }
        int i = i0 + tid;
        vout[i] = SCONST * (pv[i] - EPS_LN2 * (m0 + FLOG2(s0)));
    }
}

// ---------------------------------------------------------------------------
// scalar fallback pass (handles 4B-aligned-only Mat): block per 4 rows.
// ---------------------------------------------------------------------------
__global__ __launch_bounds__(256) void pass_scalar(const float* __restrict__ Mat,
                                                   const float* __restrict__ vin,
                                                   const float* __restrict__ pv,
                                                   float* __restrict__ vout) {
    __shared__ float sv[4096];
    int tid = threadIdx.x;
    for (int k = tid; k < 4096; k += 256) sv[k] = vin[k];
    __syncthreads();
    int w = tid >> 6, lane = tid & 63;
    int i = blockIdx.x * 4 + w;
    const float* Mrow = Mat + (size_t)i * 4096;
    float m = -1e30f, s = 0.f;
    #pragma unroll 8
    for (int k = 0; k < 64; ++k) {
        int j = lane + 64 * k;
        float u = fmaf(-SCONST, Mrow[j], sv[j]);
        float nm = fmaxf(m, u);
        s = fmaf(s, FEXP2(m - nm), FEXP2(u - nm));
        m = nm;
    }
    #pragma unroll
    for (int off = 32; off >= 1; off >>= 1) {
        float om = __shfl_xor(m, off);
        float os = __shfl_xor(s, off);
        float nm = fmaxf(m, om);
        s = fmaf(s, FEXP2(m - nm), os * FEXP2(om - nm));
        m = nm;
    }
    if (lane == 0) {
        vout[i] = SCONST * (pv[i] - EPS_LN2 * (m + FLOG2(s)));
    }
}

// ---------------------------------------------------------------------------
// fallback column pass (no CT): 64 blocks x 1024 threads.
// ---------------------------------------------------------------------------
__global__ __launch_bounds__(1024) void col_slow_kernel(const float* __restrict__ C,
                                                        const float* __restrict__ b,
                                                        const float* __restrict__ qe,
                                                        float* __restrict__ a) {
    __shared__ float sb[4096];
    __shared__ float sm[16][64];
    __shared__ float ss[16][64];
    int tid = threadIdx.x;
    for (int k = tid; k < 4096; k += 1024) sb[k] = b[k];
    __syncthreads();
    int w = tid >> 6, lane = tid & 63;
    int j = blockIdx.x * 64 + lane;
    float m = -1e30f, s = 0.f;
    #pragma unroll 4
    for (int r = 0; r < 256; ++r) {
        int i = (w << 8) + r;
        float u = fmaf(-SCONST, C[(size_t)i * 4096 + j], sb[i]);
        float nm = fmaxf(m, u);
        s = fmaf(s, FEXP2(m - nm), FEXP2(u - nm));
        m = nm;
    }
    sm[w][lane] = m; ss[w][lane] = s;
    __syncthreads();
    if (tid < 64) {
        float m0 = sm[0][tid], s0 = ss[0][tid];
        #pragma unroll
        for (int w2 = 1; w2 < 16; ++w2) {
            float m1 = sm[w2][tid], s1 = ss[w2][tid];
            float nm = fmaxf(m0, m1);
            s0 = fmaf(s0, FEXP2(m0 - nm), s1 * FEXP2(m1 - nm));
            m0 = nm;
        }
        int jj = blockIdx.x * 64 + tid;
        a[jj] = SCONST * (qe[jj] - EPS_LN2 * (m0 + FLOG2(s0)));
    }
}

// ---------------------------------------------------------------------------
// P = exp2(b_i + a_j - S*C_ij); block per row; vector C/a loads, scalar P
// stores (P base is out+1, only 4B-aligned). Partial P*C sums per row.
// ---------------------------------------------------------------------------
__global__ __launch_bounds__(256) void pcost_vec(const float4* __restrict__ C4,
                                                 const float4* __restrict__ a4,
                                                 const float* __restrict__ b,
                                                 float* __restrict__ P,
                                                 float* __restrict__ part) {
    int tid = threadIdx.x;
    int i = blockIdx.x;
    float bi = b[i];
    const float4* Crow = C4 + (size_t)i * 1024;
    float* Prow = P + (size_t)i * 4096;
    float acc = 0.f;
    #pragma unroll
    for (int k = 0; k < 4; ++k) {
        int j = tid + 256 * k;
        float4 c = Crow[j];
        float4 av = a4[j];
        float p0 = FEXP2(fmaf(-SCONST, c.x, bi + av.x));
        float p1 = FEXP2(fmaf(-SCONST, c.y, bi + av.y));
        float p2 = FEXP2(fmaf(-SCONST, c.z, bi + av.z));
        float p3 = FEXP2(fmaf(-SCONST, c.w, bi + av.w));
        Prow[4 * j + 0] = p0;
        Prow[4 * j + 1] = p1;
        Prow[4 * j + 2] = p2;
        Prow[4 * j + 3] = p3;
        acc = fmaf(p0, c.x, fmaf(p1, c.y, fmaf(p2, c.z, fmaf(p3, c.w, acc))));
    }
    #pragma unroll
    for (int off = 32; off >= 1; off >>= 1) acc += __shfl_xor(acc, off);
    __shared__ float sw[4];
    if ((tid & 63) == 0) sw[tid >> 6] = acc;
    __syncthreads();
    if (tid == 0) part[blockIdx.x] = (sw[0] + sw[1]) + (sw[2] + sw[3]);
}

__global__ __launch_bounds__(256) void pcost_scalar(const float* __restrict__ C,
                                                    const float* __restrict__ a,
                                                    const float* __restrict__ b,
                                                    float* __restrict__ P,
                                                    float* __restrict__ part) {
    int tid = threadIdx.x;
    int i = blockIdx.x;
    float bi = b[i];
    const float* Crow = C + (size_t)i * 4096;
    float* Prow = P + (size_t)i * 4096;
    float acc = 0.f;
    #pragma unroll 4
    for (int k = 0; k < 16; ++k) {
        int j = tid + 256 * k;
        float c = Crow[j];
        float Pv = FEXP2(fmaf(-SCONST, c, bi + a[j]));
        Prow[j] = Pv;
        acc = fmaf(Pv, c, acc);
    }
    #pragma unroll
    for (int off = 32; off >= 1; off >>= 1) acc += __shfl_xor(acc, off);
    __shared__ float sw[4];
    if ((tid & 63) == 0) sw[tid >> 6] = acc;
    __syncthreads();
    if (tid == 0) part[blockIdx.x] = (sw[0] + sw[1]) + (sw[2] + sw[3]);
}

__global__ __launch_bounds__(256) void reduce_kernel(const float* __restrict__ part,
                                                     float* __restrict__ out0) {
    int tid = threadIdx.x;
    float acc = 0.f;
    #pragma unroll
    for (int k = 0; k < 16; ++k) acc += part[tid + 256 * k];
    #pragma unroll
    for (int off = 32; off >= 1; off >>= 1) acc += __shfl_xor(acc, off);
    __shared__ float sw[4];
    if ((tid & 63) == 0) sw[tid >> 6] = acc;
    __syncthreads();
    if (tid == 0) out0[0] = (sw[0] + sw[1]) + (sw[2] + sw[3]);
}

// ---------------------------------------------------------------------------
extern "C" void kernel_launch(void* const* d_in, const int* in_sizes, int n_in,
                              void* d_out, int out_size, void* d_ws, size_t ws_size,
                              hipStream_t stream) {
    const float* x = (const float*)d_in[0];
    const float* y = (const float*)d_in[1];
    const float* p = (const float*)d_in[2];
    const float* q = (const float*)d_in[3];
    float* out = (float*)d_out;
    char* ws = (char*)d_ws;

    float* pe   = (float*)(ws + 0 * 16384);
    float* qe   = (float*)(ws + 1 * 16384);
    float* a    = (float*)(ws + 2 * 16384);   // S * g
    float* b    = (float*)(ws + 3 * 16384);   // S * f
    float* xn   = (float*)(ws + 4 * 16384);
    float* yn   = (float*)(ws + 5 * 16384);
    float* part = (float*)(ws + 6 * 16384);
    const size_t SMALL = 128 * 1024;
    const size_t CBYTES = NM * sizeof(float);

    // Tier A: C and CT both in ws (16B aligned, full vector path)
    // Tier B: C in ws (vector), CT at out+1 (scalar col passes)
    // Tier C: C at out+1 (scalar everything, col_slow)
    float* C;
    float* CT;
    int tier;
    if (ws_size >= SMALL + 2 * CBYTES) {
        C  = (float*)(ws + SMALL);
        CT = C + NM;
        tier = 0;
    } else if (ws_size >= SMALL + CBYTES) {
        C  = (float*)(ws + SMALL);
        CT = out + 1;
        tier = 1;
    } else {
        C  = out + 1;
        CT = nullptr;
        tier = 2;
    }

    init_kernel<<<16, 256, 0, stream>>>(x, y, p, q, pe, qe, a, xn, yn);
    cost_kernel<<<dim3(64, 64), 256, 0, stream>>>(x, y, xn, yn, C, CT);

    for (int iter = 0; iter < 10; ++iter) {
        // row pass: b = S*f from C rows, vin = a
        if (tier <= 1) {
            pass_vec<<<1024, 256, 0, stream>>>((const float4*)C, (const float4*)a, pe, b);
        } else {
            pass_scalar<<<1024, 256, 0, stream>>>(C, a, pe, b);
        }
        // col pass: a = S*g from CT rows, vin = b
        if (tier == 0) {
            pass_vec<<<1024, 256, 0, stream>>>((const float4*)CT, (const float4*)b, qe, a);
        } else if (tier == 1) {
            pass_scalar<<<1024, 256, 0, stream>>>(CT, b, qe, a);
        } else {
            col_slow_kernel<<<64, 1024, 0, stream>>>(C, b, qe, a);
        }
    }

    if (tier <= 1) {
        pcost_vec<<<4096, 256, 0, stream>>>((const float4*)C, (const float4*)a, b, out + 1, part);
    } else {
        pcost_scalar<<<4096, 256, 0, stream>>>(C, a, b, out + 1, part);
    }
    reduce_kernel<<<1, 256, 0, stream>>>(part, out);
}